// Round 1
// 472.075 us; speedup vs baseline: 1.0324x; 1.0324x over previous
//
#include <hip/hip_runtime.h>
#include <hip/hip_bf16.h>

#define NN 50000
#define HD 128
#define NL 4
#define BN_EPS 1e-5f
#define NTILES 3125

typedef __attribute__((ext_vector_type(8))) short short8;
typedef __attribute__((ext_vector_type(4))) float f32x4;

__device__ inline ushort f2bf(float f){
  uint u = __float_as_uint(f);
  uint r = (u + 0x7fffu + ((u >> 16) & 1u)) >> 16;
  return (ushort)r;
}
__device__ inline float bflo(uint u){ return __uint_as_float(u << 16); }
__device__ inline float bfhi(uint u){ return __uint_as_float(u & 0xffff0000u); }
__device__ inline uint pk2(float lo, float hi){
  return (uint)f2bf(lo) | ((uint)f2bf(hi) << 16);
}

// ---------------- cast fp32 -> bf16 ----------------
__global__ void cast_f32_bf16x4(const float* __restrict__ in, ushort* __restrict__ out, int n4){
  int i = blockIdx.x * blockDim.x + threadIdx.x;
  int stride = gridDim.x * blockDim.x;
  const float4* in4 = (const float4*)in;
  for (; i < n4; i += stride){
    float4 v = in4[i];
    ushort4 r;
    r.x = f2bf(v.x); r.y = f2bf(v.y); r.z = f2bf(v.z); r.w = f2bf(v.w);
    *(ushort4*)(out + i * 4) = r;
  }
}

__global__ void cast_weights(const float* __restrict__ w1, const float* __restrict__ w2,
                             const float* __restrict__ wf, ushort* __restrict__ wb){
  int i = blockIdx.x * 256 + threadIdx.x;
  if (i >= 36864) return;
  const float* src;
  if (i < 16384)      src = w1 + i * 4;
  else if (i < 32768) src = w2 + (i - 16384) * 4;
  else                src = wf + (i - 32768) * 4;
  float4 v = *(const float4*)src;
  ushort4 r;
  r.x = f2bf(v.x); r.y = f2bf(v.y); r.z = f2bf(v.z); r.w = f2bf(v.w);
  *(ushort4*)(wb + i * 4) = r;
}

// ---------------- CSR build ----------------
__global__ void fill1_kernel(const int* __restrict__ dst, int* __restrict__ cnt,
                             int* __restrict__ pos, int E){
  int e = (blockIdx.x * 256 + threadIdx.x) * 4;
  if (e + 4 <= E){
    int4 d = *(const int4*)(dst + e);
    int4 p;
    p.x = atomicAdd(&cnt[d.x], 1);
    p.y = atomicAdd(&cnt[d.y], 1);
    p.z = atomicAdd(&cnt[d.z], 1);
    p.w = atomicAdd(&cnt[d.w], 1);
    *(int4*)(pos + e) = p;
  } else {
    for (; e < E; ++e) pos[e] = atomicAdd(&cnt[dst[e]], 1);
  }
}

__global__ void scan1_kernel(const int* __restrict__ deg, int* __restrict__ incl,
                             int* __restrict__ bsum, int n){
  __shared__ int tmp[1024];
  int gid = blockIdx.x * 1024 + threadIdx.x;
  int v = (gid < n) ? deg[gid] : 0;
  tmp[threadIdx.x] = v;
  __syncthreads();
  for (int ofs = 1; ofs < 1024; ofs <<= 1){
    int t = tmp[threadIdx.x];
    int a = (threadIdx.x >= ofs) ? tmp[threadIdx.x - ofs] : 0;
    __syncthreads();
    tmp[threadIdx.x] = t + a;
    __syncthreads();
  }
  if (gid < n) incl[gid] = tmp[threadIdx.x];
  if (threadIdx.x == 1023) bsum[blockIdx.x] = tmp[1023];
}

// wave-parallel scan over block sums (nb <= 64)
__global__ void scan2_kernel(const int* __restrict__ bsum, int* __restrict__ base,
                             int* __restrict__ off, int nb, int n){
  int lane = threadIdx.x & 63;
  int own = (lane < nb) ? bsum[lane] : 0;
  int v = own;
#pragma unroll
  for (int ofs = 1; ofs < 64; ofs <<= 1){
    int t = __shfl_up(v, ofs);
    if (lane >= ofs) v += t;
  }
  if (lane < nb) base[lane] = v - own;
  if (lane == 63) off[n] = v;
}

__global__ void scan3_kernel(const int* __restrict__ deg, const int* __restrict__ incl,
                             const int* __restrict__ base, int* __restrict__ off, int n){
  int gid = blockIdx.x * 1024 + threadIdx.x;
  if (gid < n) off[gid] = incl[gid] - deg[gid] + base[blockIdx.x];
}

__global__ void fill2_kernel(const int* __restrict__ src, const int* __restrict__ dst,
                             const int* __restrict__ off, const int* __restrict__ pos,
                             int* __restrict__ csrc, int E){
  int e = (blockIdx.x * 256 + threadIdx.x) * 4;
  if (e + 4 <= E){
    int4 d = *(const int4*)(dst + e);
    int4 p = *(const int4*)(pos + e);
    int4 s = *(const int4*)(src + e);
    csrc[off[d.x] + p.x] = s.x;
    csrc[off[d.y] + p.y] = s.y;
    csrc[off[d.z] + p.z] = s.z;
    csrc[off[d.w] + p.w] = s.w;
  } else {
    for (; e < E; ++e) csrc[off[dst[e]] + pos[e]] = src[e];
  }
}

// ---------------- BN param computation (device helper, threads<128) ----------------
__device__ inline void bn_params_tid(const float* st, const float* gA, const float* gB,
                                     const float* bB, int mode, float* sS, float* sT){
  int c = threadIdx.x;
  if (c < 128){
    const float invN = 1.f / (float)NN;
    float mu = st[c] * invN;
    float var = fmaxf(st[128 + c] * invN - mu * mu, 0.f);
    float S, T;
    if (mode == 0){
      S = gA[c] * rsqrtf(var + BN_EPS);
      T = gB[c] - mu * S;
    } else {
      float inv2 = rsqrtf(var + BN_EPS);
      float tt = gA[c] * inv2;
      float inv3 = rsqrtf(tt * tt * var + BN_EPS);
      S = tt * inv3 * gB[c];
      T = bB[c] - mu * S;
    }
    sS[c] = S; sT[c] = T;
  }
}

// ---------------- per-node bn3(bn2(.))+relu transform: y2 -> x_next ----------------
__global__ __launch_bounds__(256) void xform_kernel(const ushort* __restrict__ y,
                                                    const float* __restrict__ statsIn,
                                                    const float* __restrict__ g2,
                                                    const float* __restrict__ g3,
                                                    const float* __restrict__ b3,
                                                    ushort* __restrict__ xo){
  __shared__ float sS[128];
  __shared__ float sT[128];
  bn_params_tid(statsIn, g2, g3, b3, 1, sS, sT);
  __syncthreads();
  int i0 = blockIdx.x * 256 + threadIdx.x;
  int cb = (i0 & 15) * 8;          // channel base, invariant across grid-stride iters
  float S[8], T[8];
#pragma unroll
  for (int k = 0; k < 8; ++k){ S[k] = sS[cb + k]; T[k] = sT[cb + k]; }
  const uint4* y4 = (const uint4*)y;
  uint4* o4 = (uint4*)xo;
  const int total = NN * 16;
  int stride = gridDim.x * 256;
  for (int i = i0; i < total; i += stride){
    uint4 v = y4[i];
    uint4 r;
    r.x = pk2(fmaxf(bflo(v.x)*S[0]+T[0],0.f), fmaxf(bfhi(v.x)*S[1]+T[1],0.f));
    r.y = pk2(fmaxf(bflo(v.y)*S[2]+T[2],0.f), fmaxf(bfhi(v.y)*S[3]+T[3],0.f));
    r.z = pk2(fmaxf(bflo(v.z)*S[4]+T[4],0.f), fmaxf(bfhi(v.z)*S[5]+T[5],0.f));
    r.w = pk2(fmaxf(bflo(v.w)*S[6]+T[6],0.f), fmaxf(bfhi(v.w)*S[7]+T[7],0.f));
    o4[i] = r;
  }
}

// ---------------- aggregation: h = x + sum(neigh x), dwordx4 gather ----------------
// 16 lanes per row (uint4 each); one wave covers 4 edges per load instruction.
// Grid-stride, 2048 persistent blocks x 4 waves (1 node per wave).
__global__ __launch_bounds__(256) void agg_kernel(const ushort* __restrict__ xb,
                                                  const int* __restrict__ off,
                                                  const int* __restrict__ csrc,
                                                  ushort* __restrict__ h){
  const uint4* x4 = (const uint4*)xb;
  uint4* h4 = (uint4*)h;
  int lane = threadIdx.x & 63;
  int grp  = lane >> 4;    // 0..3: which edge of the quad this lane serves
  int col  = lane & 15;    // 16-B chunk within the 256-B row
  for (int node = blockIdx.x * 4 + (threadIdx.x >> 6); node < NN; node += gridDim.x * 4){
    int s = off[node], e = off[node + 1];
    float a0, a1, a2, a3, a4, a5, a6, a7;
    if (grp == 0){   // self term added once
      uint4 v = x4[node * 16 + col];
      a0 = bflo(v.x); a1 = bfhi(v.x); a2 = bflo(v.y); a3 = bfhi(v.y);
      a4 = bflo(v.z); a5 = bfhi(v.z); a6 = bflo(v.w); a7 = bfhi(v.w);
    } else {
      a0=0.f;a1=0.f;a2=0.f;a3=0.f;a4=0.f;a5=0.f;a6=0.f;a7=0.f;
    }
    int j = s + grp;
    while (j + 4 < e){   // 2 gathers in flight per iteration (8 edges / wave-iter)
      int r0 = csrc[j];
      int r1 = csrc[j + 4];
      uint4 v0 = x4[r0 * 16 + col];
      uint4 v1 = x4[r1 * 16 + col];
      a0 += bflo(v0.x) + bflo(v1.x); a1 += bfhi(v0.x) + bfhi(v1.x);
      a2 += bflo(v0.y) + bflo(v1.y); a3 += bfhi(v0.y) + bfhi(v1.y);
      a4 += bflo(v0.z) + bflo(v1.z); a5 += bfhi(v0.z) + bfhi(v1.z);
      a6 += bflo(v0.w) + bflo(v1.w); a7 += bfhi(v0.w) + bfhi(v1.w);
      j += 8;
    }
    if (j < e){
      uint4 v = x4[csrc[j] * 16 + col];
      a0 += bflo(v.x); a1 += bfhi(v.x);
      a2 += bflo(v.y); a3 += bfhi(v.y);
      a4 += bflo(v.z); a5 += bfhi(v.z);
      a6 += bflo(v.w); a7 += bfhi(v.w);
    }
    // reduce across the 4 edge-groups
    a0 += __shfl_xor(a0, 16); a1 += __shfl_xor(a1, 16);
    a2 += __shfl_xor(a2, 16); a3 += __shfl_xor(a3, 16);
    a4 += __shfl_xor(a4, 16); a5 += __shfl_xor(a5, 16);
    a6 += __shfl_xor(a6, 16); a7 += __shfl_xor(a7, 16);
    a0 += __shfl_xor(a0, 32); a1 += __shfl_xor(a1, 32);
    a2 += __shfl_xor(a2, 32); a3 += __shfl_xor(a3, 32);
    a4 += __shfl_xor(a4, 32); a5 += __shfl_xor(a5, 32);
    a6 += __shfl_xor(a6, 32); a7 += __shfl_xor(a7, 32);
    if (grp == 0){
      uint4 o;
      o.x = pk2(a0, a1); o.y = pk2(a2, a3);
      o.z = pk2(a4, a5); o.w = pk2(a6, a7);
      h4[node * 16 + col] = o;
    }
  }
}

// ---------------- unified GEMM: Y = [relu(affine(A))] @ W^T + bias ----------------
// 512 threads, 8 waves, 1 tile (16 rows) per wave; grid 391.
__global__ __launch_bounds__(512) void gemm_kernel(const ushort* __restrict__ A,
                                                   const ushort* __restrict__ W,
                                                   const float* __restrict__ bias,
                                                   ushort* __restrict__ Yb,
                                                   float* __restrict__ Yf,
                                                   float* __restrict__ statsOut,
                                                   const float* __restrict__ statsIn,
                                                   const float* __restrict__ gA,
                                                   const float* __restrict__ gB,
                                                   const float* __restrict__ bB,
                                                   int mode){
  __shared__ uint4 w4[128 * 17];
  __shared__ float ssum[128];
  __shared__ float ssq[128];
  __shared__ float sS[128];
  __shared__ float sT[128];
  const uint4* Wg = (const uint4*)W;
  for (int c = threadIdx.x; c < 2048; c += 512){
    w4[(c >> 4) * 17 + (c & 15)] = Wg[c];
  }
  if (statsIn) bn_params_tid(statsIn, gA, gB, bB, mode, sS, sT);
  if (threadIdx.x < 128){ ssum[threadIdx.x] = 0.f; ssq[threadIdx.x] = 0.f; }
  __syncthreads();

  int wave = threadIdx.x >> 6;
  int lane = threadIdx.x & 63;
  int m = lane & 15, q = lane >> 4;
  int tile = blockIdx.x * 8 + wave;
  bool tv = tile < NTILES;
  const uint4* A4 = (const uint4*)A;

  f32x4 acc[8];
#pragma unroll
  for (int i = 0; i < 8; ++i) acc[i] = (f32x4)0.f;

#pragma unroll
  for (int kt = 0; kt < 4; ++kt){
    short8 af = (short8)0;
    if (tv){
      uint4 t = A4[(tile * 16 + m) * 16 + kt * 4 + q];
      if (statsIn){
        int kc = kt * 32 + q * 8;
        uint4 pk;
        pk.x = (uint)f2bf(fmaxf(bflo(t.x)*sS[kc+0]+sT[kc+0],0.f))
             | ((uint)f2bf(fmaxf(bfhi(t.x)*sS[kc+1]+sT[kc+1],0.f)) << 16);
        pk.y = (uint)f2bf(fmaxf(bflo(t.y)*sS[kc+2]+sT[kc+2],0.f))
             | ((uint)f2bf(fmaxf(bfhi(t.y)*sS[kc+3]+sT[kc+3],0.f)) << 16);
        pk.z = (uint)f2bf(fmaxf(bflo(t.z)*sS[kc+4]+sT[kc+4],0.f))
             | ((uint)f2bf(fmaxf(bfhi(t.z)*sS[kc+5]+sT[kc+5],0.f)) << 16);
        pk.w = (uint)f2bf(fmaxf(bflo(t.w)*sS[kc+6]+sT[kc+6],0.f))
             | ((uint)f2bf(fmaxf(bfhi(t.w)*sS[kc+7]+sT[kc+7],0.f)) << 16);
        t = pk;
      }
      af = *(short8*)&t;
    }
#pragma unroll
    for (int to = 0; to < 8; ++to){
      uint4 bw = w4[(to * 16 + m) * 17 + kt * 4 + q];
      acc[to] = __builtin_amdgcn_mfma_f32_16x16x32_bf16(af, *(short8*)&bw, acc[to], 0, 0, 0);
    }
  }

  bool dost = (statsOut != nullptr);
#pragma unroll
  for (int to = 0; to < 8; ++to){
    int col = to * 16 + m;
    float bc = bias[col];
    float ls = 0.f, lq = 0.f;
    if (tv){
#pragma unroll
      for (int r = 0; r < 4; ++r){
        float v = acc[to][r] + bc;
        int row = tile * 16 + q * 4 + r;
        if (Yb) Yb[row * 128 + col] = __builtin_bit_cast(ushort, f2bf(v));
        else    Yf[row * 128 + col] = v;
        ls += v; lq += v * v;
      }
    }
    if (dost){
      ls += __shfl_xor(ls, 16); lq += __shfl_xor(lq, 16);
      ls += __shfl_xor(ls, 32); lq += __shfl_xor(lq, 32);
      if (tv && q == 0){ atomicAdd(&ssum[col], ls); atomicAdd(&ssq[col], lq); }
    }
  }
  if (dost){
    __syncthreads();
    if (threadIdx.x < 128){
      atomicAdd(&statsOut[threadIdx.x], ssum[threadIdx.x]);
      atomicAdd(&statsOut[128 + threadIdx.x], ssq[threadIdx.x]);
    }
  }
}

extern "C" void kernel_launch(void* const* d_in, const int* in_sizes, int n_in,
                              void* d_out, int out_size, void* d_ws, size_t ws_size,
                              hipStream_t stream) {
  const float* x     = (const float*)d_in[0];
  const int*   ei    = (const int*)d_in[1];
  const float* fc1_w = (const float*)d_in[2];
  const float* fc1_b = (const float*)d_in[3];
  const float* bn1_g = (const float*)d_in[4];
  const float* bn1_b = (const float*)d_in[5];
  const float* fc2_w = (const float*)d_in[6];
  const float* fc2_b = (const float*)d_in[7];
  const float* bn2_g = (const float*)d_in[8];
  const float* bn3_g = (const float*)d_in[10];
  const float* bn3_b = (const float*)d_in[11];
  const float* fc_w  = (const float*)d_in[12];
  const float* fc_b  = (const float*)d_in[13];

  int E = in_sizes[1] / 2;
  const int* srcp = ei;
  const int* dstp = ei + E;

  char* ws = (char*)d_ws;
  int*    off    = (int*)(ws + 0);           // (N+1) ints
  int*    cnt    = (int*)(ws + 200064);      // N ints
  int*    pos    = (int*)(ws + 400128);      // E ints
  int*    csrc   = (int*)(ws + 3600128);     // E ints (aliased as `incl` pre-fill2)
  ushort* wb     = (ushort*)(ws + 6800128);  // 147456 bf16
  float*  stats  = (float*)(ws + 7095040);   // 8 slices x 256 floats
  int*    sscr   = (int*)(ws + 7103232);     // scan bsum/base
  ushort* xb     = (ushort*)(ws + 7104256);  // N*128 bf16 (x / x_next ping)
  ushort* hb     = (ushort*)(ws + 19904256); // N*128 bf16
  ushort* y1b    = (ushort*)(ws + 32704256); // N*128 bf16
  ushort* y2b    = (ushort*)(ws + 45504256); // N*128 bf16

  int* incl = csrc;
  int* bsum = sscr;
  int* base = sscr + 64;

  hipMemsetAsync(cnt, 0, 200064, stream);
  hipMemsetAsync(stats, 0, 8192, stream);

  cast_f32_bf16x4<<<2048, 256, 0, stream>>>(x, xb, NN * HD / 4);
  cast_weights<<<144, 256, 0, stream>>>(fc1_w, fc2_w, fc_w, wb);

  const int EB4 = (E / 4 + 255) / 256 + 1;
  const int SB = (NN + 1023) / 1024;
  fill1_kernel<<<EB4, 256, 0, stream>>>(dstp, cnt, pos, E);
  scan1_kernel<<<SB, 1024, 0, stream>>>(cnt, incl, bsum, NN);
  scan2_kernel<<<1, 64, 0, stream>>>(bsum, base, off, SB, NN);
  scan3_kernel<<<SB, 1024, 0, stream>>>(cnt, incl, base, off, NN);
  fill2_kernel<<<EB4, 256, 0, stream>>>(srcp, dstp, off, pos, csrc, E);

  const int gb = (NTILES + 7) / 8;  // 391 blocks x 8 waves

  for (int i = 0; i < NL; ++i){
    // plain gather-sum (input already has bn23+relu applied by xform for i>0)
    agg_kernel<<<2048, 256, 0, stream>>>(xb, off, csrc, hb);
    // fc1: hb -> y1b (bf16), stats1
    gemm_kernel<<<gb, 512, 0, stream>>>(hb, wb + i * 16384, fc1_b + i * 128,
                                        y1b, nullptr, stats + i * 512,
                                        nullptr, nullptr, nullptr, nullptr, 0);
    // fc2: relu(bn1(y1b)) -> y2b (bf16), stats2; bn1 params inline from stats1
    gemm_kernel<<<gb, 512, 0, stream>>>(y1b, wb + 65536 + i * 16384, fc2_b + i * 128,
                                        y2b, nullptr, stats + i * 512 + 256,
                                        stats + i * 512, bn1_g + i * 128,
                                        bn1_b + i * 128, nullptr, 0);
    // materialize x_next = relu(bn3(bn2(y2b))) for the next layer's aggregation
    if (i < NL - 1){
      xform_kernel<<<1024, 256, 0, stream>>>(y2b, stats + i * 512 + 256,
                                             bn2_g + i * 128, bn3_g + i * 128,
                                             bn3_b + i * 128, xb);
    }
  }

  // classifier: relu(bn3(bn2(y2b)))@fc_w^T + fc_b -> f32 out; bn23 params inline
  gemm_kernel<<<gb, 512, 0, stream>>>(y2b, wb + 131072, fc_b,
                                      nullptr, (float*)d_out, nullptr,
                                      stats + 3 * 512 + 256, bn2_g + 384,
                                      bn3_g + 384, bn3_b + 384, 1);
}